// Round 8
// baseline (270.423 us; speedup 1.0000x reference)
//
#include <hip/hip_runtime.h>
#include <math.h>

// Problem constants
// x: (16,64,3,32,32) x2 concat -> (1024,6,32,32)
// conv1 6->64 k3 p1 -> BN -> ReLU -> pool2 -> (1024,64,16,16)
// conv2 64->64 k3 p1 -> BN -> ReLU -> pool2 -> (1024,64,8,8) = feats (1024,4096)
// RNN T=64 steps over feats rows n=b*64+t ; head -> sigmoid (16,1)

typedef __attribute__((ext_vector_type(8))) short s8v;   // 8 bf16 (4 VGPRs)
typedef __attribute__((ext_vector_type(4))) float f32x4;

__device__ __forceinline__ unsigned short f2bf(float f) {
  union { float f; unsigned u; } x; x.f = f;
  return (unsigned short)((x.u + 0x7FFFu + ((x.u >> 16) & 1u)) >> 16);  // RNE
}
__device__ __forceinline__ float bf2f(unsigned short u) {
  union { unsigned u; float f; } x; x.u = ((unsigned)u) << 16; return x.f;
}
// fast tanh: 1 - 2/(e^{2x}+1); inf-safe via rcp (e=inf -> 0 -> +1; e->0 -> -1)
__device__ __forceinline__ float ftanh(float x) {
  float e = __expf(2.f * x);
  return 1.f - 2.f * __builtin_amdgcn_rcpf(e + 1.f);
}

// ---------------------------------------------------------------------------
// w1 pack: fp32 [co][ci=6][kh][kw] -> bf16 [kh][64co][32k], k = kw*6+ci,
// ZEROS at k in [18,32) -- these multiply the A-side overread garbage.
// ---------------------------------------------------------------------------
__global__ __launch_bounds__(256)
void w1_pack(const float* __restrict__ w1, unsigned short* __restrict__ wB1)
{
  int i = blockIdx.x*256 + threadIdx.x;   // 3*64*32 = 6144
  if (i < 6144) {
    int kh = i >> 11, rem = i & 2047, co = rem >> 5, k2 = rem & 31;
    unsigned short v = 0;
    if (k2 < 18) {
      int kw = k2 / 6, ci = k2 - 6*kw;
      v = f2bf(w1[co*54 + ci*9 + kh*3 + kw]);
    }
    wB1[i] = v;
  }
}

// ---------------------------------------------------------------------------
// conv1 via MFMA implicit GEMM, computed ONCE. grid 1024, block 256 (4 waves).
// Epilogue: per-channel sum/sumsq + 2x2 pooled max/min bf16 channel-last.
// ---------------------------------------------------------------------------
__global__ __launch_bounds__(256, 4)
void conv1_mfma(const float* __restrict__ x1, const float* __restrict__ x2,
                const unsigned short* __restrict__ wB1,
                float* __restrict__ part,
                unsigned short* __restrict__ pmax1, unsigned short* __restrict__ pmin1)
{
  __shared__ unsigned xin[3688];          // 34 rows x 108 dwords + 16 pad
  __shared__ float wred[4][4][16][2];
  const int n = blockIdx.x, tid = threadIdx.x;
  const int w = tid >> 6, lane = tid & 63;
  const int q = lane >> 4, r = lane & 15;

  // B fragments, whole kernel in regs: bf[kh][t], co = 16t + r, k0 = 8q
  s8v bf[3][4];
  #pragma unroll
  for (int kh = 0; kh < 3; ++kh)
    #pragma unroll
    for (int t = 0; t < 4; ++t)
      bf[kh][t] = *(const s8v*)&wB1[kh*2048 + (((t<<4)+r)<<5) + (q<<3)];

  // zero ALL of xin (incl. pad tail) -- overread garbage must be finite
  #pragma unroll
  for (int k = 0; k < 15; ++k) {
    int i = tid + (k<<8);
    if (i < 3688) xin[i] = 0;
  }
  __syncthreads();
  // interior fill: dword (y+1)*108 + (x+1)*3 + cp packs bf16{ci=2cp,2cp+1}
  #pragma unroll
  for (int k = 0; k < 12; ++k) {
    int i = tid + (k<<8);     // 0..3071
    int cp = i >> 10, p = i & 1023;
    int y = p >> 5, x = p & 31;
    float lo, hi;
    if (cp == 0)      { lo = x1[n*3072 + p];        hi = x1[n*3072 + 1024 + p]; }
    else if (cp == 1) { lo = x1[n*3072 + 2048 + p]; hi = x2[n*3072 + p];        }
    else              { lo = x2[n*3072 + 1024 + p]; hi = x2[n*3072 + 2048 + p]; }
    xin[(y+1)*108 + (x+1)*3 + cp] = (unsigned)f2bf(lo) | ((unsigned)f2bf(hi) << 16);
  }
  __syncthreads();

  float st[4], sq[4];
  #pragma unroll
  for (int t = 0; t < 4; ++t) { st[t] = 0.f; sq[t] = 0.f; }
  float pmx[4][2], pmn[4][2];

  #pragma unroll 1
  for (int xb = 0; xb < 2; ++xb) {
    const int xbase = xb << 4;
    #pragma unroll 2
    for (int j = 0; j < 8; ++j) {           // y = 8w + j
      const int y = (w << 3) + j;
      f32x4 acc[4];
      #pragma unroll
      for (int t = 0; t < 4; ++t) acc[t] = (f32x4){0.f,0.f,0.f,0.f};
      #pragma unroll
      for (int kh = 0; kh < 3; ++kh) {      // k-step == kh slice
        int dw = (y + kh)*108 + 3*(xbase + r) + (q << 2);
        union { unsigned u[4]; s8v v; } af;
        af.u[0] = xin[dw];   af.u[1] = xin[dw+1];
        af.u[2] = xin[dw+2]; af.u[3] = xin[dw+3];
        #pragma unroll
        for (int t = 0; t < 4; ++t)
          acc[t] = __builtin_amdgcn_mfma_f32_16x16x32_bf16(af.v, bf[kh][t], acc[t], 0, 0, 0);
      }
      #pragma unroll
      for (int t = 0; t < 4; ++t) {
        st[t] += acc[t][0]+acc[t][1]+acc[t][2]+acc[t][3];
        sq[t] = fmaf(acc[t][0],acc[t][0], fmaf(acc[t][1],acc[t][1],
                fmaf(acc[t][2],acc[t][2], fmaf(acc[t][3],acc[t][3], sq[t]))));
      }
      if ((j & 1) == 0) {                   // even y: stash x-pair max/min
        #pragma unroll
        for (int t = 0; t < 4; ++t) {
          pmx[t][0] = fmaxf(acc[t][0], acc[t][1]); pmx[t][1] = fmaxf(acc[t][2], acc[t][3]);
          pmn[t][0] = fminf(acc[t][0], acc[t][1]); pmn[t][1] = fminf(acc[t][2], acc[t][3]);
        }
      } else {                              // odd y: combine + write pooled
        const int py = y >> 1;
        #pragma unroll
        for (int t = 0; t < 4; ++t) {
          int co = (t << 4) + r;
          #pragma unroll
          for (int pp = 0; pp < 2; ++pp) {
            float mx = fmaxf(pmx[t][pp], fmaxf(acc[t][2*pp], acc[t][2*pp+1]));
            float mn = fminf(pmn[t][pp], fminf(acc[t][2*pp], acc[t][2*pp+1]));
            int pxp = (xb << 3) + (q << 1) + pp;
            int o = (((n << 8) + (py << 4) + pxp) << 6) + co;
            pmax1[o] = f2bf(mx);
            pmin1[o] = f2bf(mn);
          }
        }
      }
    }
  }

  #pragma unroll
  for (int t = 0; t < 4; ++t) {
    float s = st[t], ss = sq[t];
    s  += __shfl_xor(s, 16);  s  += __shfl_xor(s, 32);
    ss += __shfl_xor(ss, 16); ss += __shfl_xor(ss, 32);
    if (q == 0) { wred[w][t][r][0] = s; wred[w][t][r][1] = ss; }
  }
  __syncthreads();
  if (tid < 64) {
    float s = 0.f, ss = 0.f;
    #pragma unroll
    for (int wv = 0; wv < 4; ++wv) {
      s  += wred[wv][tid >> 4][tid & 15][0];
      ss += wred[wv][tid >> 4][tid & 15][1];
    }
    part[tid*2048 + n*2]     = s;     // layout [c][n][2]
    part[tid*2048 + n*2 + 1] = ss;
  }
}

// ---------------------------------------------------------------------------
// BN finalize: per-channel mean/var -> scale/shift.  grid 64, block 256.
// ---------------------------------------------------------------------------
__global__ __launch_bounds__(256)
void bn_finalize(const float* __restrict__ part, const float* __restrict__ g,
                 const float* __restrict__ beta, float inv_cnt, float* __restrict__ bn)
{
  __shared__ float red[8];
  const int c = blockIdx.x, tid = threadIdx.x;
  float s = 0.f, ss = 0.f;
  for (int n = tid; n < 1024; n += 256) {
    s  += part[c*2048 + n*2];
    ss += part[c*2048 + n*2 + 1];
  }
  #pragma unroll
  for (int d = 32; d; d >>= 1) { s += __shfl_xor(s, d); ss += __shfl_xor(ss, d); }
  if ((tid & 63) == 0) { red[(tid>>6)*2] = s; red[(tid>>6)*2+1] = ss; }
  __syncthreads();
  if (tid == 0) {
    float S  = red[0]+red[2]+red[4]+red[6];
    float SS = red[1]+red[3]+red[5]+red[7];
    float m  = S * inv_cnt;
    float var = SS * inv_cnt - m*m;
    float sc = g[c] * rsqrtf(var + 1e-5f);
    bn[c]    = sc;
    bn[64+c] = beta[c] - m*sc;
  }
}

// ---------------------------------------------------------------------------
// w2 pack: fp32 [co][ci][kh][kw] -> bf16 [khw][co][ci] with the ci-chunk
// XOR-swizzle ((ci>>3)^(co&7)) pre-applied so conv2's LDS copy is linear.
// ---------------------------------------------------------------------------
__global__ __launch_bounds__(256)
void w2_pack(const float* __restrict__ w2, unsigned short* __restrict__ wB)
{
  int i = blockIdx.x*256 + threadIdx.x;   // 9*64*64 = 36864
  if (i < 36864) {
    int khw = i >> 12, rem = i & 4095, co = rem >> 6, ci = rem & 63;
    int chunk = (ci >> 3) ^ (co & 7);
    wB[khw*4096 + co*64 + chunk*8 + (ci & 7)] = f2bf(w2[co*576 + ci*9 + khw]);
  }
}

// ---------------------------------------------------------------------------
// Qw pack: fp32 [100][4196] (first 4096 cols) -> bf16 [112][4096],
// rows 100..111 zeroed (N padded to 7x16 MFMA tiles).
// ---------------------------------------------------------------------------
__global__ __launch_bounds__(256)
void qw_pack(const float* __restrict__ Qw, unsigned short* __restrict__ qB)
{
  int i = blockIdx.x*256 + threadIdx.x;   // 112*4096 = 458752
  if (i < 458752) {
    int j = i >> 12, k = i & 4095;
    qB[i] = (j < 100) ? f2bf(Qw[j*4196 + k]) : (unsigned short)0;
  }
}

// ---------------------------------------------------------------------------
// RNN weight pack: Rw fp32 (100x400) -> bf16 rB[112][416] (zero pad);
// Qw recurrent cols (100x100 at col 4096) -> bf16 qrB[112][128] (zero pad).
// ---------------------------------------------------------------------------
__global__ __launch_bounds__(256)
void rq_pack(const float* __restrict__ Rw, const float* __restrict__ Qw,
             unsigned short* __restrict__ rB, unsigned short* __restrict__ qrB)
{
  int i = blockIdx.x*256 + threadIdx.x;   // 46592 + 14336 = 60928
  if (i < 46592) {
    int o = i / 416, k = i - o*416;
    rB[i] = (o < 100 && k < 400) ? f2bf(Rw[o*400 + k]) : (unsigned short)0;
  } else if (i < 60928) {
    int j = i - 46592;
    int o = j >> 7, kr = j & 127;
    qrB[j] = (o < 100 && kr < 100) ? f2bf(Qw[o*4196 + 4096 + kr]) : (unsigned short)0;
  }
}

// ---------------------------------------------------------------------------
// conv2 via MFMA implicit GEMM. grid 1024 (one image), block 256 (4 waves).
// Staging FUSES conv1's BN affine + ReLU. Pooled raw outputs stored bf16.
// ---------------------------------------------------------------------------
__global__ __launch_bounds__(256)
void conv2_mfma(const unsigned short* __restrict__ pmax1,
                const unsigned short* __restrict__ pmin1,
                const float* __restrict__ bn1,
                const unsigned short* __restrict__ wB,
                float* __restrict__ part,
                unsigned short* __restrict__ pmax2, unsigned short* __restrict__ pmin2)
{
  __shared__ unsigned short xin[324*64];   // 41472 B
  __shared__ unsigned short wL[9*64*64];   // 73728 B
  __shared__ float wred[4][4][16][2];      // 2 KB
  __shared__ float bnL[128];
  const int n = blockIdx.x, tid = threadIdx.x;
  const int w = tid >> 6, lane = tid & 63;
  const int q = lane >> 4, col = lane & 15;

  if (tid < 128) bnL[tid] = bn1[tid];
  // ---- stage weights (linear copy; swizzle pre-applied by w2_pack) ----
  {
    const s8v* src = (const s8v*)wB;
    s8v* dst = (s8v*)wL;
    #pragma unroll
    for (int i = 0; i < 18; ++i) dst[tid + (i<<8)] = src[tid + (i<<8)];
  }
  __syncthreads();   // bnL ready
  // ---- stage input 18x18x64 bf16 = relu(affine(pooled conv1)), halo zeros,
  //      swizzled 16B chunks ----
  {
    #pragma unroll
    for (int k = 0; k < 11; ++k) {
      int i = tid + (k<<8);
      if (i < 324*8) {
        int L = i >> 3, s = i & 7;
        int y = L / 18, x = L - y*18;
        s8v v = (s8v){0,0,0,0,0,0,0,0};
        if (y >= 1 && y <= 16 && x >= 1 && x <= 16) {
          int idx = (((n<<8) + ((y-1)<<4) + (x-1))<<6) + (s<<3);
          s8v mx = *(const s8v*)&pmax1[idx];
          s8v mn = *(const s8v*)&pmin1[idx];
          #pragma unroll
          for (int e = 0; e < 8; ++e) {
            int ci = (s<<3) + e;
            float sc = bnL[ci], sh = bnL[64+ci];
            float vv = bf2f((unsigned short)(sc >= 0.f ? mx[e] : mn[e]));
            v[e] = (short)f2bf(fmaxf(fmaf(vv, sc, sh), 0.f));
          }
        }
        *(s8v*)((char*)xin + L*128 + (((s ^ (L & 7)) << 4))) = v;
      }
    }
  }
  __syncthreads();

  f32x4 acc[4][4];   // [mtile][ntile]
  #pragma unroll
  for (int mt = 0; mt < 4; ++mt)
    #pragma unroll
    for (int t = 0; t < 4; ++t)
      acc[mt][t] = (f32x4){0.f,0.f,0.f,0.f};

  const int py0 = w << 2;   // wave's 4 image rows
  #pragma unroll 1
  for (int khw = 0; khw < 9; ++khw) {
    const int kh = khw / 3, kw = khw - 3*kh;
    const char* wslice = (const char*)wL + khw*8192;
    #pragma unroll
    for (int ks = 0; ks < 2; ++ks) {       // ci0 = 32*ks
      const int chunk = (ks << 2) + q;     // 16B-chunk of k within line
      s8v bfrag[4];
      #pragma unroll
      for (int t = 0; t < 4; ++t) {
        int co = (t << 4) + col;
        bfrag[t] = *(const s8v*)(wslice + co*128 + (((chunk ^ (co & 7)) << 4)));
      }
      #pragma unroll
      for (int mt = 0; mt < 4; ++mt) {
        int L = (py0 + mt + kh)*18 + (col + kw);
        s8v afrag = *(const s8v*)((const char*)xin + L*128 + (((chunk ^ (L & 7)) << 4)));
        #pragma unroll
        for (int t = 0; t < 4; ++t)
          acc[mt][t] = __builtin_amdgcn_mfma_f32_16x16x32_bf16(afrag, bfrag[t], acc[mt][t], 0, 0, 0);
      }
    }
  }

  // ---- stats: per-channel sum / sumsq over this block's 256 pixels ----
  #pragma unroll
  for (int t = 0; t < 4; ++t) {
    float s = 0.f, ss = 0.f;
    #pragma unroll
    for (int mt = 0; mt < 4; ++mt)
      #pragma unroll
      for (int r = 0; r < 4; ++r) {
        float v = acc[mt][t][r];
        s += v; ss = fmaf(v, v, ss);
      }
    s  += __shfl_xor(s, 16);  s  += __shfl_xor(s, 32);
    ss += __shfl_xor(ss, 16); ss += __shfl_xor(ss, 32);
    if (q == 0) { wred[w][t][col][0] = s; wred[w][t][col][1] = ss; }
  }
  __syncthreads();
  if (tid < 64) {
    float s = 0.f, ss = 0.f;
    #pragma unroll
    for (int wv = 0; wv < 4; ++wv) {
      s  += wred[wv][tid >> 4][tid & 15][0];
      ss += wred[wv][tid >> 4][tid & 15][1];
    }
    part[tid*2048 + n*2]     = s;
    part[tid*2048 + n*2 + 1] = ss;
  }

  // ---- 2x2 pooled max AND min of raw conv (affine applied later), bf16 ----
  #pragma unroll
  for (int t = 0; t < 4; ++t) {
    int co = (t << 4) + col;
    #pragma unroll
    for (int mp = 0; mp < 2; ++mp) {          // vertical pair (rows 2mp,2mp+1)
      f32x4 a0 = acc[2*mp][t], a1 = acc[2*mp+1][t];
      float mx0 = fmaxf(fmaxf(a0[0], a0[1]), fmaxf(a1[0], a1[1]));
      float mx1 = fmaxf(fmaxf(a0[2], a0[3]), fmaxf(a1[2], a1[3]));
      float mn0 = fminf(fminf(a0[0], a0[1]), fminf(a1[0], a1[1]));
      float mn1 = fminf(fminf(a0[2], a0[3]), fminf(a1[2], a1[3]));
      int pyp = (w << 1) + mp;                // pooled y
      int base = ((n*64 + co) << 6) + (pyp << 3) + (q << 1);  // feats c*64+p
      pmax2[base] = f2bf(mx0); pmax2[base+1] = f2bf(mx1);
      pmin2[base] = f2bf(mn0); pmin2[base+1] = f2bf(mn1);
    }
  }
}

// ---------------------------------------------------------------------------
// preQ partials via MFMA, fusing conv2's BN affine + ReLU into the A-frag
// load. No LDS. grid (16 mblocks x 16 ksplits), block 256.
// part layout [ks][1024][112] fp32.
// ---------------------------------------------------------------------------
__global__ __launch_bounds__(256)
void preq_mfma(const unsigned short* __restrict__ pmax2,
               const unsigned short* __restrict__ pmin2,
               const float* __restrict__ bn2,
               const unsigned short* __restrict__ qB,
               float* __restrict__ part)
{
  const int mb = blockIdx.x, ks = blockIdx.y, tid = threadIdx.x;
  const int w = tid >> 6, lane = tid & 63;
  const int q = lane >> 4, col = lane & 15;
  const int m = (mb << 6) + (w << 4) + col;    // A row this lane loads
  const int k00 = ks << 8;

  f32x4 acc[7];
  #pragma unroll
  for (int t = 0; t < 7; ++t) acc[t] = (f32x4){0.f,0.f,0.f,0.f};

  #pragma unroll 2
  for (int kk = 0; kk < 8; ++kk) {
    const int k = k00 + (kk << 5) + (q << 3);  // 8-aligned, one c per chunk
    const int c = k >> 6;
    const float sc = bn2[c], sh = bn2[64 + c];
    s8v mx = *(const s8v*)&pmax2[m*4096 + k];
    s8v mn = *(const s8v*)&pmin2[m*4096 + k];
    s8v a;
    #pragma unroll
    for (int e = 0; e < 8; ++e) {
      float vv = bf2f((unsigned short)(sc >= 0.f ? mx[e] : mn[e]));
      a[e] = (short)f2bf(fmaxf(fmaf(vv, sc, sh), 0.f));
    }
    #pragma unroll
    for (int t = 0; t < 7; ++t) {
      s8v b = *(const s8v*)&qB[(((t << 4) + col) << 12) + k];
      acc[t] = __builtin_amdgcn_mfma_f32_16x16x32_bf16(a, b, acc[t], 0, 0, 0);
    }
  }

  // C: col=lane&15 = j16, row=4q+r = m-row within the wave's 16-row tile
  float* dst = part + ks*114688 + ((mb << 6) + (w << 4) + (q << 2))*112;
  #pragma unroll
  for (int t = 0; t < 7; ++t)
    #pragma unroll
    for (int r = 0; r < 4; ++r)
      dst[r*112 + (t << 4) + col] = acc[t][r];
}

// preQ2[(t*16+b)*100+j] = sum_ks part[ks][n][j] + Qb[j], n = b*64+t.
__global__ __launch_bounds__(256)
void preq_reduce(const float* __restrict__ part, const float* __restrict__ Qb,
                 float* __restrict__ preQ2)
{
  int idx = blockIdx.x*256 + threadIdx.x;  // 102400 exact
  if (idx < 1024*100) {
    int n = idx / 100, j = idx - n*100;
    float s = Qb[j];
    #pragma unroll
    for (int ks = 0; ks < 16; ++ks) s += part[ks*114688 + n*112 + j];
    int b = n >> 6, t = n & 63;
    preQ2[((t << 4) + b)*100 + j] = s;
  }
}

// ---------------------------------------------------------------------------
// Fused RNN + head, ALL 16 batch rows in ONE block (R7: 16-block version was
// 94us at 1.4% occupancy -- latency bound). 8 waves; M=16 via MFMA.
// Wave w (w<7) owns output tile o in [16w,16w+16). Rw bf16 in 52 VGPRs,
// Qw-recurrent in 16 VGPRs. Ha fp32 in LDS + bf16 shadow haB (A-operand).
// LDS strides padded (haB 424, rtB 136 shorts) for conflict-free b128 reads.
// ---------------------------------------------------------------------------
__global__ __launch_bounds__(512)
void rnn_fused(const float* __restrict__ preQ2,
               const unsigned short* __restrict__ rB,
               const unsigned short* __restrict__ qrB,
               const float* __restrict__ Rb,
               const float* __restrict__ Ow, const float* __restrict__ Ob,
               const float* __restrict__ f1w, const float* __restrict__ f1b,
               const float* __restrict__ f2w, const float* __restrict__ f2b,
               float* __restrict__ out)
{
  __shared__ __align__(16) float ha[6400];            // [b][a*100+o] fp32
  __shared__ __align__(16) unsigned short haB[16*424]; // bf16 shadow, stride 424
  __shared__ __align__(16) unsigned short rtB[16*136]; // Rt bf16, stride 136
  __shared__ float qtL[16*112];
  __shared__ __align__(16) float olL[16*128];
  __shared__ __align__(16) float f1L[16*64];
  const int tid = threadIdx.x;
  const int w = tid >> 6, lane = tid & 63;
  const int q = lane >> 4, col = lane & 15;
  const int o16 = (w << 4) + col;

  // persistent B-fragments
  s8v rw[13], qw[4];
  float rbv = 0.f;
  if (w < 7) {
    #pragma unroll
    for (int kk = 0; kk < 13; ++kk)
      rw[kk] = *(const s8v*)&rB[o16*416 + (kk << 5) + (q << 3)];
    #pragma unroll
    for (int kk = 0; kk < 4; ++kk)
      qw[kk] = *(const s8v*)&qrB[o16*128 + (kk << 5) + (q << 3)];
    rbv = (o16 < 100) ? Rb[o16] : 0.f;
  }

  // zero-init state (pads included; pads never rewritten)
  for (int i = tid; i < 6400; i += 512) ha[i] = 0.f;
  for (int i = tid; i < 16*424; i += 512) haB[i] = 0;
  for (int i = tid; i < 16*136; i += 512) rtB[i] = 0;

  // update-phase precomputed constants (static-indexed arrays, rule #20)
  float A_[13], B_[13];
  int qo_[13], hb_[13];
  #pragma unroll
  for (int j = 0; j < 13; ++j) {
    int idx = tid + (j << 9);
    if (idx >= 6400) idx = 6399;   // inactive slot (j==12, tid>=256) -- safe dummy
    int bb = idx / 400; int rem = idx - bb*400;
    int a = rem / 100;
    float Aa = (a == 0) ? 0.f : (a == 1) ? 0.25f : (a == 2) ? 0.5f : 0.95f;
    A_[j] = Aa; B_[j] = 1.f - Aa;
    qo_[j] = bb*112 + (rem - a*100);
    hb_[j] = bb*424 + rem;
  }
  __syncthreads();

  for (int t = 0; t < 64; ++t) {
    // prefetch this step's preQ adds (hides L2 latency under R-matvec)
    float pqv[4];
    if (w < 7) {
      #pragma unroll
      for (int r = 0; r < 4; ++r)
        pqv[r] = (o16 < 100) ? preQ2[((t << 4) + (q << 2) + r)*100 + o16] : 0.f;
    }
    // R: Rt[b][o] = ftanh(sum_k Hf[b][k]*Rw[o][k] + Rb[o]); 13 MFMAs, 2 chains
    if (w < 7) {
      f32x4 r0 = (f32x4){0.f,0.f,0.f,0.f}, r1 = (f32x4){0.f,0.f,0.f,0.f};
      #pragma unroll
      for (int kk = 0; kk < 13; kk += 2) {
        s8v af = *(const s8v*)&haB[col*424 + (kk << 5) + (q << 3)];
        r0 = __builtin_amdgcn_mfma_f32_16x16x32_bf16(af, rw[kk], r0, 0, 0, 0);
        if (kk + 1 < 13) {
          s8v af2 = *(const s8v*)&haB[col*424 + ((kk+1) << 5) + (q << 3)];
          r1 = __builtin_amdgcn_mfma_f32_16x16x32_bf16(af2, rw[kk+1], r1, 0, 0, 0);
        }
      }
      #pragma unroll
      for (int r = 0; r < 4; ++r)
        rtB[((q << 2) + r)*136 + o16] = f2bf(ftanh(r0[r] + r1[r] + rbv));
    }
    __syncthreads();
    // Q: Qt[b][o] = ftanh(preQ + sum_kr Rt[b][kr]*Qwrec[o][kr]); 4 MFMAs
    if (w < 7) {
      f32x4 qacc = (f32x4){0.f,0.f,0.f,0.f};
      #pragma unroll
      for (int kk = 0; kk < 4; ++kk) {
        s8v af = *(const s8v*)&rtB[col*136 + (kk << 5) + (q << 3)];
        qacc = __builtin_amdgcn_mfma_f32_16x16x32_bf16(af, qw[kk], qacc, 0, 0, 0);
      }
      #pragma unroll
      for (int r = 0; r < 4; ++r)
        qtL[((q << 2) + r)*112 + o16] = ftanh(qacc[r] + pqv[r]);
    }
    __syncthreads();
    // update: Ha = A*Ha + (1-A)*Qt  (fp32) + bf16 shadow write
    #pragma unroll
    for (int j = 0; j < 13; ++j) {
      if (j < 12 || tid < 256) {
        int idx = tid + (j << 9);
        float hv = fmaf(A_[j], ha[idx], B_[j]*qtL[qo_[j]]);
        ha[idx] = hv;
        haB[hb_[j]] = f2bf(hv);
      }
    }
    __syncthreads();
  }

  // head: out_last = tanh(Hf @ Ow^T + Ob)  (16x128, K=400)
  {
    const int b = tid >> 5, jb = tid & 31;
    const float* hp = &ha[b*400];
    #pragma unroll 1
    for (int jj = 0; jj < 4; ++jj) {
      int j = jb + (jj << 5);
      const float* wp = &Ow[j*400];
      float a2 = Ob[j];
      #pragma unroll 4
      for (int k = 0; k < 400; k += 4) {
        float4 h4 = *(const float4*)&hp[k];
        float4 w4 = *(const float4*)&wp[k];
        a2 = fmaf(h4.x, w4.x, fmaf(h4.y, w4.y, fmaf(h4.z, w4.z, fmaf(h4.w, w4.w, a2))));
      }
      olL[b*128 + j] = ftanh(a2);
    }
  }
  __syncthreads();
  // fc1: relu(ol @ f1w^T + f1b)  (16x64, K=128)
  {
    const int b = tid >> 5, jb = tid & 31;
    const float* op = &olL[b*128];
    #pragma unroll 1
    for (int jj = 0; jj < 2; ++jj) {
      int j = jb + (jj << 5);
      const float* wp = &f1w[j*128];
      float a2 = f1b[j];
      #pragma unroll 4
      for (int k = 0; k < 128; k += 4) {
        float4 o4 = *(const float4*)&op[k];
        float4 w4 = *(const float4*)&wp[k];
        a2 = fmaf(o4.x, w4.x, fmaf(o4.y, w4.y, fmaf(o4.z, w4.z, fmaf(o4.w, w4.w, a2))));
      }
      f1L[b*64 + j] = fmaxf(a2, 0.f);
    }
  }
  __syncthreads();
  // fc2 + sigmoid
  if (tid < 16) {
    float a2 = f2b[0];
    #pragma unroll 8
    for (int k = 0; k < 64; ++k) a2 = fmaf(f2w[k], f1L[tid*64 + k], a2);
    out[tid] = __builtin_amdgcn_rcpf(1.f + __expf(-a2));
  }
}

// ---------------------------------------------------------------------------
extern "C" void kernel_launch(void* const* d_in, const int* in_sizes, int n_in,
                              void* d_out, int out_size, void* d_ws, size_t ws_size,
                              hipStream_t stream) {
  (void)in_sizes; (void)n_in; (void)out_size; (void)ws_size;
  const float* x1   = (const float*)d_in[0];
  const float* x2   = (const float*)d_in[1];
  const float* c1w  = (const float*)d_in[2];
  // d_in[3] conv1_b: cancels in BN
  const float* bn1g = (const float*)d_in[4];
  const float* bn1b = (const float*)d_in[5];
  const float* c2w  = (const float*)d_in[6];
  // d_in[7] conv2_b: cancels in BN
  const float* bn2g = (const float*)d_in[8];
  const float* bn2b = (const float*)d_in[9];
  const float* Rw   = (const float*)d_in[10];
  const float* Rb   = (const float*)d_in[11];
  const float* Qw   = (const float*)d_in[12];
  const float* Qb   = (const float*)d_in[13];
  const float* Ow   = (const float*)d_in[14];
  const float* Ob   = (const float*)d_in[15];
  const float* f1w  = (const float*)d_in[16];
  const float* f1b  = (const float*)d_in[17];
  const float* f2w  = (const float*)d_in[18];
  const float* f2b  = (const float*)d_in[19];
  float* outp = (float*)d_out;

  // workspace layout (bytes); total ~90 MB
  char* wsb = (char*)d_ws;
  unsigned short* pmax1 = (unsigned short*)wsb;                 // 33,554,432 B
  unsigned short* pmin1 = (unsigned short*)(wsb + 33554432);    // 33,554,432 B
  unsigned short* pmax2 = (unsigned short*)(wsb + 67108864);    //  8,388,608 B
  unsigned short* pmin2 = (unsigned short*)(wsb + 75497472);    //  8,388,608 B
  float* part1  = (float*)(wsb + 83886080);                     // 524,288 B
  float* part2  = part1 + 131072;                               // 524,288 B
  float* bn1    = part2 + 131072;                               // 512 B
  float* bn2    = bn1 + 128;                                    // 512 B
  float* preQ2  = bn2 + 128;                                    // 409,600 B
  unsigned short* wB1 = (unsigned short*)(preQ2 + 102400);      // 12,288 B
  unsigned short* wB2 = wB1 + 6144;                             // 73,728 B
  unsigned short* qB  = wB2 + 36864;                            // 917,504 B
  unsigned short* rB  = qB + 458752;                            // 93,184 B
  unsigned short* qrB = rB + 46592;                             // 28,672 B
  float* pqpart = (float*)(qrB + 14336);                        // 7,340,032 B

  w1_pack<<<24, 256, 0, stream>>>(c1w, wB1);
  w2_pack<<<144, 256, 0, stream>>>(c2w, wB2);
  qw_pack<<<1792, 256, 0, stream>>>(Qw, qB);
  rq_pack<<<238, 256, 0, stream>>>(Rw, Qw, rB, qrB);
  conv1_mfma<<<1024, 256, 0, stream>>>(x1, x2, wB1, part1, pmax1, pmin1);
  bn_finalize<<<64, 256, 0, stream>>>(part1, bn1g, bn1b, 1.f/1048576.f, bn1);
  conv2_mfma<<<1024, 256, 0, stream>>>(pmax1, pmin1, bn1, wB2, part2, pmax2, pmin2);
  bn_finalize<<<64, 256, 0, stream>>>(part2, bn2g, bn2b, 1.f/262144.f, bn2);
  preq_mfma<<<dim3(16,16), 256, 0, stream>>>(pmax2, pmin2, bn2, qB, pqpart);
  preq_reduce<<<400, 256, 0, stream>>>(pqpart, Qb, preQ2);
  rnn_fused<<<1, 512, 0, stream>>>(preQ2, rB, qrB, Rb, Ow, Ob, f1w, f1b, f2w, f2b, outp);
}

// Round 9
// 255.341 us; speedup vs baseline: 1.0591x; 1.0591x over previous
//
#include <hip/hip_runtime.h>
#include <math.h>

// Problem constants
// x: (16,64,3,32,32) x2 concat -> (1024,6,32,32)
// conv1 6->64 k3 p1 -> BN -> ReLU -> pool2 -> (1024,64,16,16)
// conv2 64->64 k3 p1 -> BN -> ReLU -> pool2 -> (1024,64,8,8) = feats (1024,4096)
// RNN T=64 steps over feats rows n=b*64+t ; head -> sigmoid (16,1)

typedef __attribute__((ext_vector_type(8))) short s8v;   // 8 bf16 (4 VGPRs)
typedef __attribute__((ext_vector_type(4))) float f32x4;

__device__ __forceinline__ unsigned short f2bf(float f) {
  union { float f; unsigned u; } x; x.f = f;
  return (unsigned short)((x.u + 0x7FFFu + ((x.u >> 16) & 1u)) >> 16);  // RNE
}
__device__ __forceinline__ float bf2f(unsigned short u) {
  union { unsigned u; float f; } x; x.u = ((unsigned)u) << 16; return x.f;
}
// fast tanh: 1 - 2/(e^{2x}+1); inf-safe via rcp (e=inf -> 0 -> +1; e->0 -> -1)
__device__ __forceinline__ float ftanh(float x) {
  float e = __expf(2.f * x);
  return 1.f - 2.f * __builtin_amdgcn_rcpf(e + 1.f);
}

// ---------------------------------------------------------------------------
// w1 pack: fp32 [co][ci=6][kh][kw] -> bf16 [kh][64co][32k], k = kw*6+ci,
// ZEROS at k in [18,32) -- these multiply the A-side overread garbage.
// ---------------------------------------------------------------------------
__global__ __launch_bounds__(256)
void w1_pack(const float* __restrict__ w1, unsigned short* __restrict__ wB1)
{
  int i = blockIdx.x*256 + threadIdx.x;   // 3*64*32 = 6144
  if (i < 6144) {
    int kh = i >> 11, rem = i & 2047, co = rem >> 5, k2 = rem & 31;
    unsigned short v = 0;
    if (k2 < 18) {
      int kw = k2 / 6, ci = k2 - 6*kw;
      v = f2bf(w1[co*54 + ci*9 + kh*3 + kw]);
    }
    wB1[i] = v;
  }
}

// ---------------------------------------------------------------------------
// conv1 via MFMA implicit GEMM, computed ONCE. grid 1024, block 256 (4 waves).
// Epilogue: per-channel sum/sumsq + 2x2 pooled max/min bf16 channel-last.
// ---------------------------------------------------------------------------
__global__ __launch_bounds__(256, 4)
void conv1_mfma(const float* __restrict__ x1, const float* __restrict__ x2,
                const unsigned short* __restrict__ wB1,
                float* __restrict__ part,
                unsigned short* __restrict__ pmax1, unsigned short* __restrict__ pmin1)
{
  __shared__ unsigned xin[3688];          // 34 rows x 108 dwords + 16 pad
  __shared__ float wred[4][4][16][2];
  const int n = blockIdx.x, tid = threadIdx.x;
  const int w = tid >> 6, lane = tid & 63;
  const int q = lane >> 4, r = lane & 15;

  // B fragments, whole kernel in regs: bf[kh][t], co = 16t + r, k0 = 8q
  s8v bf[3][4];
  #pragma unroll
  for (int kh = 0; kh < 3; ++kh)
    #pragma unroll
    for (int t = 0; t < 4; ++t)
      bf[kh][t] = *(const s8v*)&wB1[kh*2048 + (((t<<4)+r)<<5) + (q<<3)];

  // zero ALL of xin (incl. pad tail) -- overread garbage must be finite
  #pragma unroll
  for (int k = 0; k < 15; ++k) {
    int i = tid + (k<<8);
    if (i < 3688) xin[i] = 0;
  }
  __syncthreads();
  // interior fill: dword (y+1)*108 + (x+1)*3 + cp packs bf16{ci=2cp,2cp+1}
  #pragma unroll
  for (int k = 0; k < 12; ++k) {
    int i = tid + (k<<8);     // 0..3071
    int cp = i >> 10, p = i & 1023;
    int y = p >> 5, x = p & 31;
    float lo, hi;
    if (cp == 0)      { lo = x1[n*3072 + p];        hi = x1[n*3072 + 1024 + p]; }
    else if (cp == 1) { lo = x1[n*3072 + 2048 + p]; hi = x2[n*3072 + p];        }
    else              { lo = x2[n*3072 + 1024 + p]; hi = x2[n*3072 + 2048 + p]; }
    xin[(y+1)*108 + (x+1)*3 + cp] = (unsigned)f2bf(lo) | ((unsigned)f2bf(hi) << 16);
  }
  __syncthreads();

  float st[4], sq[4];
  #pragma unroll
  for (int t = 0; t < 4; ++t) { st[t] = 0.f; sq[t] = 0.f; }
  float pmx[4][2], pmn[4][2];

  #pragma unroll 1
  for (int xb = 0; xb < 2; ++xb) {
    const int xbase = xb << 4;
    #pragma unroll 2
    for (int j = 0; j < 8; ++j) {           // y = 8w + j
      const int y = (w << 3) + j;
      f32x4 acc[4];
      #pragma unroll
      for (int t = 0; t < 4; ++t) acc[t] = (f32x4){0.f,0.f,0.f,0.f};
      #pragma unroll
      for (int kh = 0; kh < 3; ++kh) {      // k-step == kh slice
        int dw = (y + kh)*108 + 3*(xbase + r) + (q << 2);
        union { unsigned u[4]; s8v v; } af;
        af.u[0] = xin[dw];   af.u[1] = xin[dw+1];
        af.u[2] = xin[dw+2]; af.u[3] = xin[dw+3];
        #pragma unroll
        for (int t = 0; t < 4; ++t)
          acc[t] = __builtin_amdgcn_mfma_f32_16x16x32_bf16(af.v, bf[kh][t], acc[t], 0, 0, 0);
      }
      #pragma unroll
      for (int t = 0; t < 4; ++t) {
        st[t] += acc[t][0]+acc[t][1]+acc[t][2]+acc[t][3];
        sq[t] = fmaf(acc[t][0],acc[t][0], fmaf(acc[t][1],acc[t][1],
                fmaf(acc[t][2],acc[t][2], fmaf(acc[t][3],acc[t][3], sq[t]))));
      }
      if ((j & 1) == 0) {                   // even y: stash x-pair max/min
        #pragma unroll
        for (int t = 0; t < 4; ++t) {
          pmx[t][0] = fmaxf(acc[t][0], acc[t][1]); pmx[t][1] = fmaxf(acc[t][2], acc[t][3]);
          pmn[t][0] = fminf(acc[t][0], acc[t][1]); pmn[t][1] = fminf(acc[t][2], acc[t][3]);
        }
      } else {                              // odd y: combine + write pooled
        const int py = y >> 1;
        #pragma unroll
        for (int t = 0; t < 4; ++t) {
          int co = (t << 4) + r;
          #pragma unroll
          for (int pp = 0; pp < 2; ++pp) {
            float mx = fmaxf(pmx[t][pp], fmaxf(acc[t][2*pp], acc[t][2*pp+1]));
            float mn = fminf(pmn[t][pp], fminf(acc[t][2*pp], acc[t][2*pp+1]));
            int pxp = (xb << 3) + (q << 1) + pp;
            int o = (((n << 8) + (py << 4) + pxp) << 6) + co;
            pmax1[o] = f2bf(mx);
            pmin1[o] = f2bf(mn);
          }
        }
      }
    }
  }

  #pragma unroll
  for (int t = 0; t < 4; ++t) {
    float s = st[t], ss = sq[t];
    s  += __shfl_xor(s, 16);  s  += __shfl_xor(s, 32);
    ss += __shfl_xor(ss, 16); ss += __shfl_xor(ss, 32);
    if (q == 0) { wred[w][t][r][0] = s; wred[w][t][r][1] = ss; }
  }
  __syncthreads();
  if (tid < 64) {
    float s = 0.f, ss = 0.f;
    #pragma unroll
    for (int wv = 0; wv < 4; ++wv) {
      s  += wred[wv][tid >> 4][tid & 15][0];
      ss += wred[wv][tid >> 4][tid & 15][1];
    }
    part[tid*2048 + n*2]     = s;     // layout [c][n][2]
    part[tid*2048 + n*2 + 1] = ss;
  }
}

// ---------------------------------------------------------------------------
// BN finalize: per-channel mean/var -> scale/shift.  grid 64, block 256.
// ---------------------------------------------------------------------------
__global__ __launch_bounds__(256)
void bn_finalize(const float* __restrict__ part, const float* __restrict__ g,
                 const float* __restrict__ beta, float inv_cnt, float* __restrict__ bn)
{
  __shared__ float red[8];
  const int c = blockIdx.x, tid = threadIdx.x;
  float s = 0.f, ss = 0.f;
  for (int n = tid; n < 1024; n += 256) {
    s  += part[c*2048 + n*2];
    ss += part[c*2048 + n*2 + 1];
  }
  #pragma unroll
  for (int d = 32; d; d >>= 1) { s += __shfl_xor(s, d); ss += __shfl_xor(ss, d); }
  if ((tid & 63) == 0) { red[(tid>>6)*2] = s; red[(tid>>6)*2+1] = ss; }
  __syncthreads();
  if (tid == 0) {
    float S  = red[0]+red[2]+red[4]+red[6];
    float SS = red[1]+red[3]+red[5]+red[7];
    float m  = S * inv_cnt;
    float var = SS * inv_cnt - m*m;
    float sc = g[c] * rsqrtf(var + 1e-5f);
    bn[c]    = sc;
    bn[64+c] = beta[c] - m*sc;
  }
}

// ---------------------------------------------------------------------------
// w2 pack: fp32 [co][ci][kh][kw] -> bf16 [khw][co][ci] with the ci-chunk
// XOR-swizzle ((ci>>3)^(co&7)) pre-applied so conv2's LDS copy is linear.
// ---------------------------------------------------------------------------
__global__ __launch_bounds__(256)
void w2_pack(const float* __restrict__ w2, unsigned short* __restrict__ wB)
{
  int i = blockIdx.x*256 + threadIdx.x;   // 9*64*64 = 36864
  if (i < 36864) {
    int khw = i >> 12, rem = i & 4095, co = rem >> 6, ci = rem & 63;
    int chunk = (ci >> 3) ^ (co & 7);
    wB[khw*4096 + co*64 + chunk*8 + (ci & 7)] = f2bf(w2[co*576 + ci*9 + khw]);
  }
}

// ---------------------------------------------------------------------------
// Qw pack: fp32 [100][4196] (first 4096 cols) -> bf16 [112][4096],
// rows 100..111 zeroed (N padded to 7x16 MFMA tiles).
// ---------------------------------------------------------------------------
__global__ __launch_bounds__(256)
void qw_pack(const float* __restrict__ Qw, unsigned short* __restrict__ qB)
{
  int i = blockIdx.x*256 + threadIdx.x;   // 112*4096 = 458752
  if (i < 458752) {
    int j = i >> 12, k = i & 4095;
    qB[i] = (j < 100) ? f2bf(Qw[j*4196 + k]) : (unsigned short)0;
  }
}

// ---------------------------------------------------------------------------
// RNN weight pack: Rw fp32 (100x400) -> bf16 rB[112][416] (zero pad);
// Qw recurrent cols (100x100 at col 4096) -> bf16 qrB[112][128] (zero pad).
// ---------------------------------------------------------------------------
__global__ __launch_bounds__(256)
void rq_pack(const float* __restrict__ Rw, const float* __restrict__ Qw,
             unsigned short* __restrict__ rB, unsigned short* __restrict__ qrB)
{
  int i = blockIdx.x*256 + threadIdx.x;   // 46592 + 14336 = 60928
  if (i < 46592) {
    int o = i / 416, k = i - o*416;
    rB[i] = (o < 100 && k < 400) ? f2bf(Rw[o*400 + k]) : (unsigned short)0;
  } else if (i < 60928) {
    int j = i - 46592;
    int o = j >> 7, kr = j & 127;
    qrB[j] = (o < 100 && kr < 100) ? f2bf(Qw[o*4196 + 4096 + kr]) : (unsigned short)0;
  }
}

// ---------------------------------------------------------------------------
// conv2 via MFMA implicit GEMM. grid 1024 (one image), block 256 (4 waves).
// Staging FUSES conv1's BN affine + ReLU. Pooled raw outputs stored bf16.
// ---------------------------------------------------------------------------
__global__ __launch_bounds__(256)
void conv2_mfma(const unsigned short* __restrict__ pmax1,
                const unsigned short* __restrict__ pmin1,
                const float* __restrict__ bn1,
                const unsigned short* __restrict__ wB,
                float* __restrict__ part,
                unsigned short* __restrict__ pmax2, unsigned short* __restrict__ pmin2)
{
  __shared__ unsigned short xin[324*64];   // 41472 B
  __shared__ unsigned short wL[9*64*64];   // 73728 B
  __shared__ float wred[4][4][16][2];      // 2 KB
  __shared__ float bnL[128];
  const int n = blockIdx.x, tid = threadIdx.x;
  const int w = tid >> 6, lane = tid & 63;
  const int q = lane >> 4, col = lane & 15;

  if (tid < 128) bnL[tid] = bn1[tid];
  // ---- stage weights (linear copy; swizzle pre-applied by w2_pack) ----
  {
    const s8v* src = (const s8v*)wB;
    s8v* dst = (s8v*)wL;
    #pragma unroll
    for (int i = 0; i < 18; ++i) dst[tid + (i<<8)] = src[tid + (i<<8)];
  }
  __syncthreads();   // bnL ready
  // ---- stage input 18x18x64 bf16 = relu(affine(pooled conv1)), halo zeros,
  //      swizzled 16B chunks ----
  {
    #pragma unroll
    for (int k = 0; k < 11; ++k) {
      int i = tid + (k<<8);
      if (i < 324*8) {
        int L = i >> 3, s = i & 7;
        int y = L / 18, x = L - y*18;
        s8v v = (s8v){0,0,0,0,0,0,0,0};
        if (y >= 1 && y <= 16 && x >= 1 && x <= 16) {
          int idx = (((n<<8) + ((y-1)<<4) + (x-1))<<6) + (s<<3);
          s8v mx = *(const s8v*)&pmax1[idx];
          s8v mn = *(const s8v*)&pmin1[idx];
          #pragma unroll
          for (int e = 0; e < 8; ++e) {
            int ci = (s<<3) + e;
            float sc = bnL[ci], sh = bnL[64+ci];
            float vv = bf2f((unsigned short)(sc >= 0.f ? mx[e] : mn[e]));
            v[e] = (short)f2bf(fmaxf(fmaf(vv, sc, sh), 0.f));
          }
        }
        *(s8v*)((char*)xin + L*128 + (((s ^ (L & 7)) << 4))) = v;
      }
    }
  }
  __syncthreads();

  f32x4 acc[4][4];   // [mtile][ntile]
  #pragma unroll
  for (int mt = 0; mt < 4; ++mt)
    #pragma unroll
    for (int t = 0; t < 4; ++t)
      acc[mt][t] = (f32x4){0.f,0.f,0.f,0.f};

  const int py0 = w << 2;   // wave's 4 image rows
  #pragma unroll 1
  for (int khw = 0; khw < 9; ++khw) {
    const int kh = khw / 3, kw = khw - 3*kh;
    const char* wslice = (const char*)wL + khw*8192;
    #pragma unroll
    for (int ks = 0; ks < 2; ++ks) {       // ci0 = 32*ks
      const int chunk = (ks << 2) + q;     // 16B-chunk of k within line
      s8v bfrag[4];
      #pragma unroll
      for (int t = 0; t < 4; ++t) {
        int co = (t << 4) + col;
        bfrag[t] = *(const s8v*)(wslice + co*128 + (((chunk ^ (co & 7)) << 4)));
      }
      #pragma unroll
      for (int mt = 0; mt < 4; ++mt) {
        int L = (py0 + mt + kh)*18 + (col + kw);
        s8v afrag = *(const s8v*)((const char*)xin + L*128 + (((chunk ^ (L & 7)) << 4)));
        #pragma unroll
        for (int t = 0; t < 4; ++t)
          acc[mt][t] = __builtin_amdgcn_mfma_f32_16x16x32_bf16(afrag, bfrag[t], acc[mt][t], 0, 0, 0);
      }
    }
  }

  // ---- stats: per-channel sum / sumsq over this block's 256 pixels ----
  #pragma unroll
  for (int t = 0; t < 4; ++t) {
    float s = 0.f, ss = 0.f;
    #pragma unroll
    for (int mt = 0; mt < 4; ++mt)
      #pragma unroll
      for (int r = 0; r < 4; ++r) {
        float v = acc[mt][t][r];
        s += v; ss = fmaf(v, v, ss);
      }
    s  += __shfl_xor(s, 16);  s  += __shfl_xor(s, 32);
    ss += __shfl_xor(ss, 16); ss += __shfl_xor(ss, 32);
    if (q == 0) { wred[w][t][col][0] = s; wred[w][t][col][1] = ss; }
  }
  __syncthreads();
  if (tid < 64) {
    float s = 0.f, ss = 0.f;
    #pragma unroll
    for (int wv = 0; wv < 4; ++wv) {
      s  += wred[wv][tid >> 4][tid & 15][0];
      ss += wred[wv][tid >> 4][tid & 15][1];
    }
    part[tid*2048 + n*2]     = s;
    part[tid*2048 + n*2 + 1] = ss;
  }

  // ---- 2x2 pooled max AND min of raw conv (affine applied later), bf16 ----
  #pragma unroll
  for (int t = 0; t < 4; ++t) {
    int co = (t << 4) + col;
    #pragma unroll
    for (int mp = 0; mp < 2; ++mp) {          // vertical pair (rows 2mp,2mp+1)
      f32x4 a0 = acc[2*mp][t], a1 = acc[2*mp+1][t];
      float mx0 = fmaxf(fmaxf(a0[0], a0[1]), fmaxf(a1[0], a1[1]));
      float mx1 = fmaxf(fmaxf(a0[2], a0[3]), fmaxf(a1[2], a1[3]));
      float mn0 = fminf(fminf(a0[0], a0[1]), fminf(a1[0], a1[1]));
      float mn1 = fminf(fminf(a0[2], a0[3]), fminf(a1[2], a1[3]));
      int pyp = (w << 1) + mp;                // pooled y
      int base = ((n*64 + co) << 6) + (pyp << 3) + (q << 1);  // feats c*64+p
      pmax2[base] = f2bf(mx0); pmax2[base+1] = f2bf(mx1);
      pmin2[base] = f2bf(mn0); pmin2[base+1] = f2bf(mn1);
    }
  }
}

// ---------------------------------------------------------------------------
// preQ partials via MFMA, fusing conv2's BN affine + ReLU into the A-frag
// load. No LDS. grid (16 mblocks x 16 ksplits), block 256.
// part layout [ks][1024][112] fp32.
// ---------------------------------------------------------------------------
__global__ __launch_bounds__(256)
void preq_mfma(const unsigned short* __restrict__ pmax2,
               const unsigned short* __restrict__ pmin2,
               const float* __restrict__ bn2,
               const unsigned short* __restrict__ qB,
               float* __restrict__ part)
{
  const int mb = blockIdx.x, ks = blockIdx.y, tid = threadIdx.x;
  const int w = tid >> 6, lane = tid & 63;
  const int q = lane >> 4, col = lane & 15;
  const int m = (mb << 6) + (w << 4) + col;    // A row this lane loads
  const int k00 = ks << 8;

  f32x4 acc[7];
  #pragma unroll
  for (int t = 0; t < 7; ++t) acc[t] = (f32x4){0.f,0.f,0.f,0.f};

  #pragma unroll 2
  for (int kk = 0; kk < 8; ++kk) {
    const int k = k00 + (kk << 5) + (q << 3);  // 8-aligned, one c per chunk
    const int c = k >> 6;
    const float sc = bn2[c], sh = bn2[64 + c];
    s8v mx = *(const s8v*)&pmax2[m*4096 + k];
    s8v mn = *(const s8v*)&pmin2[m*4096 + k];
    s8v a;
    #pragma unroll
    for (int e = 0; e < 8; ++e) {
      float vv = bf2f((unsigned short)(sc >= 0.f ? mx[e] : mn[e]));
      a[e] = (short)f2bf(fmaxf(fmaf(vv, sc, sh), 0.f));
    }
    #pragma unroll
    for (int t = 0; t < 7; ++t) {
      s8v b = *(const s8v*)&qB[(((t << 4) + col) << 12) + k];
      acc[t] = __builtin_amdgcn_mfma_f32_16x16x32_bf16(a, b, acc[t], 0, 0, 0);
    }
  }

  // C: col=lane&15 = j16, row=4q+r = m-row within the wave's 16-row tile
  float* dst = part + ks*114688 + ((mb << 6) + (w << 4) + (q << 2))*112;
  #pragma unroll
  for (int t = 0; t < 7; ++t)
    #pragma unroll
    for (int r = 0; r < 4; ++r)
      dst[r*112 + (t << 4) + col] = acc[t][r];
}

// preQ2[(t*16+b)*100+j] = sum_ks part[ks][n][j] + Qb[j], n = b*64+t.
__global__ __launch_bounds__(256)
void preq_reduce(const float* __restrict__ part, const float* __restrict__ Qb,
                 float* __restrict__ preQ2)
{
  int idx = blockIdx.x*256 + threadIdx.x;  // 102400 exact
  if (idx < 1024*100) {
    int n = idx / 100, j = idx - n*100;
    float s = Qb[j];
    #pragma unroll
    for (int ks = 0; ks < 16; ++ks) s += part[ks*114688 + n*112 + j];
    int b = n >> 6, t = n & 63;
    preQ2[((t << 4) + b)*100 + j] = s;
  }
}

// ---------------------------------------------------------------------------
// Fused RNN + head, all 16 batch rows, ONE block (single CU for locality).
// R9 redesign after R8 regression (165us, 3 barriers + LDS-roundtrip update):
//  - fp32 Ha master lives IN REGISTERS of the Q-phase C-fragment owners
//    (lane holds Qt[b=4q+reg][o16]; Ha[b][a][o16] = 16 regs). Update = 16
//    in-reg FMAs + 4 ds_write_b16 (bf16 shadow haB for next A-operand).
//  - 2 barriers/step (was 3), no qtL/fp32-ha LDS traffic in the loop.
//  - R-phase: 13 MFMAs in 4 chains (dep depth 4); Q: 4 MFMAs in 2 chains.
// ---------------------------------------------------------------------------
__global__ __launch_bounds__(512)
void rnn_fused(const float* __restrict__ preQ2,
               const unsigned short* __restrict__ rB,
               const unsigned short* __restrict__ qrB,
               const float* __restrict__ Rb,
               const float* __restrict__ Ow, const float* __restrict__ Ob,
               const float* __restrict__ f1w, const float* __restrict__ f1b,
               const float* __restrict__ f2w, const float* __restrict__ f2b,
               float* __restrict__ out)
{
  __shared__ __align__(16) unsigned short haB[16*424]; // bf16 Hf, stride 424
  __shared__ __align__(16) unsigned short rtB[16*136]; // bf16 Rt, stride 136
  __shared__ __align__(16) float haF[6400];            // fp32 Hf for head (end)
  __shared__ __align__(16) float olL[16*128];
  __shared__ __align__(16) float f1L[16*64];
  const int tid = threadIdx.x;
  const int w = tid >> 6, lane = tid & 63;
  const int q = lane >> 4, col = lane & 15;
  const int o16 = (w << 4) + col;
  const bool act = (w < 7);
  const bool valid = act && (o16 < 100);

  // persistent B-fragments
  s8v rw[13], qw[4];
  float rbv = 0.f;
  if (act) {
    #pragma unroll
    for (int kk = 0; kk < 13; ++kk)
      rw[kk] = *(const s8v*)&rB[o16*416 + (kk << 5) + (q << 3)];
    #pragma unroll
    for (int kk = 0; kk < 4; ++kk)
      qw[kk] = *(const s8v*)&qrB[o16*128 + (kk << 5) + (q << 3)];
    rbv = valid ? Rb[o16] : 0.f;
  }

  // fp32 Ha master, in registers: hrA[a][reg], b = 4q+reg, o = o16
  float hr0[4] = {0.f,0.f,0.f,0.f};   // a=0 (A=0)
  float hr1[4] = {0.f,0.f,0.f,0.f};   // a=1 (A=0.25)
  float hr2[4] = {0.f,0.f,0.f,0.f};   // a=2 (A=0.5)
  float hr3[4] = {0.f,0.f,0.f,0.f};   // a=3 (A=0.95)

  for (int i = tid; i < 16*424; i += 512) haB[i] = 0;
  for (int i = tid; i < 16*136; i += 512) rtB[i] = 0;
  __syncthreads();

  for (int t = 0; t < 64; ++t) {
    // prefetch preQ adds (L2) -- hidden under R-phase
    float pqv[4];
    if (act) {
      #pragma unroll
      for (int reg = 0; reg < 4; ++reg)
        pqv[reg] = valid ? preQ2[(((t << 4) + (q << 2) + reg))*100 + o16] : 0.f;
    }
    // R: Rt = ftanh(Hf @ Rw^T + Rb); 13 MFMAs, 4 independent chains
    if (act) {
      f32x4 r0 = (f32x4){0.f,0.f,0.f,0.f}, r1 = r0, r2 = r0, r3 = r0;
      #pragma unroll
      for (int kk = 0; kk < 13; ++kk) {
        s8v af = *(const s8v*)&haB[col*424 + (kk << 5) + (q << 3)];
        if ((kk & 3) == 0)      r0 = __builtin_amdgcn_mfma_f32_16x16x32_bf16(af, rw[kk], r0, 0, 0, 0);
        else if ((kk & 3) == 1) r1 = __builtin_amdgcn_mfma_f32_16x16x32_bf16(af, rw[kk], r1, 0, 0, 0);
        else if ((kk & 3) == 2) r2 = __builtin_amdgcn_mfma_f32_16x16x32_bf16(af, rw[kk], r2, 0, 0, 0);
        else                    r3 = __builtin_amdgcn_mfma_f32_16x16x32_bf16(af, rw[kk], r3, 0, 0, 0);
      }
      f32x4 rs = (r0 + r1) + (r2 + r3);
      #pragma unroll
      for (int reg = 0; reg < 4; ++reg)
        rtB[((q << 2) + reg)*136 + o16] = f2bf(ftanh(rs[reg] + rbv));
    }
    __syncthreads();
    // Q: Qt = ftanh(preQ + Rt @ Qwrec^T); 4 MFMAs, 2 chains; then in-reg update
    if (act) {
      f32x4 q0 = (f32x4){0.f,0.f,0.f,0.f}, q1 = q0;
      #pragma unroll
      for (int kk = 0; kk < 4; ++kk) {
        s8v af = *(const s8v*)&rtB[col*136 + (kk << 5) + (q << 3)];
        if (kk & 1) q1 = __builtin_amdgcn_mfma_f32_16x16x32_bf16(af, qw[kk], q1, 0, 0, 0);
        else        q0 = __builtin_amdgcn_mfma_f32_16x16x32_bf16(af, qw[kk], q0, 0, 0, 0);
      }
      f32x4 qs = q0 + q1;
      #pragma unroll
      for (int reg = 0; reg < 4; ++reg) {
        float qt = ftanh(qs[reg] + pqv[reg]);
        hr0[reg] = qt;                                   // A=0
        hr1[reg] = fmaf(0.25f, hr1[reg], 0.75f*qt);
        hr2[reg] = fmaf(0.50f, hr2[reg], 0.50f*qt);
        hr3[reg] = fmaf(0.95f, hr3[reg], 0.05f*qt);
        if (valid) {
          unsigned short* hp = &haB[((q << 2) + reg)*424 + o16];
          hp[0]   = f2bf(hr0[reg]);
          hp[100] = f2bf(hr1[reg]);
          hp[200] = f2bf(hr2[reg]);
          hp[300] = f2bf(hr3[reg]);
        }
      }
    }
    __syncthreads();
  }

  // dump fp32 Ha to LDS for the head
  if (valid) {
    #pragma unroll
    for (int reg = 0; reg < 4; ++reg) {
      float* hp = &haF[((q << 2) + reg)*400 + o16];
      hp[0] = hr0[reg]; hp[100] = hr1[reg]; hp[200] = hr2[reg]; hp[300] = hr3[reg];
    }
  }
  __syncthreads();

  // head: out_last = tanh(Hf @ Ow^T + Ob)  (16x128, K=400)
  {
    const int b = tid >> 5, jb = tid & 31;
    const float* hp = &haF[b*400];
    #pragma unroll 1
    for (int jj = 0; jj < 4; ++jj) {
      int j = jb + (jj << 5);
      const float* wp = &Ow[j*400];
      float a2 = Ob[j];
      #pragma unroll 4
      for (int k = 0; k < 400; k += 4) {
        float4 h4 = *(const float4*)&hp[k];
        float4 w4 = *(const float4*)&wp[k];
        a2 = fmaf(h4.x, w4.x, fmaf(h4.y, w4.y, fmaf(h4.z, w4.z, fmaf(h4.w, w4.w, a2))));
      }
      olL[b*128 + j] = ftanh(a2);
    }
  }
  __syncthreads();
  // fc1: relu(ol @ f1w^T + f1b)  (16x64, K=128)
  {
    const int b = tid >> 5, jb = tid & 31;
    const float* op = &olL[b*128];
    #pragma unroll 1
    for (int jj = 0; jj < 2; ++jj) {
      int j = jb + (jj << 5);
      const float* wp = &f1w[j*128];
      float a2 = f1b[j];
      #pragma unroll 4
      for (int k = 0; k < 128; k += 4) {
        float4 o4 = *(const float4*)&op[k];
        float4 w4 = *(const float4*)&wp[k];
        a2 = fmaf(o4.x, w4.x, fmaf(o4.y, w4.y, fmaf(o4.z, w4.z, fmaf(o4.w, w4.w, a2))));
      }
      f1L[b*64 + j] = fmaxf(a2, 0.f);
    }
  }
  __syncthreads();
  // fc2 + sigmoid
  if (tid < 16) {
    float a2 = f2b[0];
    #pragma unroll 8
    for (int k = 0; k < 64; ++k) a2 = fmaf(f2w[k], f1L[tid*64 + k], a2);
    out[tid] = __builtin_amdgcn_rcpf(1.f + __expf(-a2));
  }
}

// ---------------------------------------------------------------------------
extern "C" void kernel_launch(void* const* d_in, const int* in_sizes, int n_in,
                              void* d_out, int out_size, void* d_ws, size_t ws_size,
                              hipStream_t stream) {
  (void)in_sizes; (void)n_in; (void)out_size; (void)ws_size;
  const float* x1   = (const float*)d_in[0];
  const float* x2   = (const float*)d_in[1];
  const float* c1w  = (const float*)d_in[2];
  // d_in[3] conv1_b: cancels in BN
  const float* bn1g = (const float*)d_in[4];
  const float* bn1b = (const float*)d_in[5];
  const float* c2w  = (const float*)d_in[6];
  // d_in[7] conv2_b: cancels in BN
  const float* bn2g = (const float*)d_in[8];
  const float* bn2b = (const float*)d_in[9];
  const float* Rw   = (const float*)d_in[10];
  const float* Rb   = (const float*)d_in[11];
  const float* Qw   = (const float*)d_in[12];
  const float* Qb   = (const float*)d_in[13];
  const float* Ow   = (const float*)d_in[14];
  const float* Ob   = (const float*)d_in[15];
  const float* f1w  = (const float*)d_in[16];
  const float* f1b  = (const float*)d_in[17];
  const float* f2w  = (const float*)d_in[18];
  const float* f2b  = (const float*)d_in[19];
  float* outp = (float*)d_out;

  // workspace layout (bytes); total ~90 MB
  char* wsb = (char*)d_ws;
  unsigned short* pmax1 = (unsigned short*)wsb;                 // 33,554,432 B
  unsigned short* pmin1 = (unsigned short*)(wsb + 33554432);    // 33,554,432 B
  unsigned short* pmax2 = (unsigned short*)(wsb + 67108864);    //  8,388,608 B
  unsigned short* pmin2 = (unsigned short*)(wsb + 75497472);    //  8,388,608 B
  float* part1  = (float*)(wsb + 83886080);                     // 524,288 B
  float* part2  = part1 + 131072;                               // 524,288 B
  float* bn1    = part2 + 131072;                               // 512 B
  float* bn2    = bn1 + 128;                                    // 512 B
  float* preQ2  = bn2 + 128;                                    // 409,600 B
  unsigned short* wB1 = (unsigned short*)(preQ2 + 102400);      // 12,288 B
  unsigned short* wB2 = wB1 + 6144;                             // 73,728 B
  unsigned short* qB  = wB2 + 36864;                            // 917,504 B
  unsigned short* rB  = qB + 458752;                            // 93,184 B
  unsigned short* qrB = rB + 46592;                             // 28,672 B
  float* pqpart = (float*)(qrB + 14336);                        // 7,340,032 B

  w1_pack<<<24, 256, 0, stream>>>(c1w, wB1);
  w2_pack<<<144, 256, 0, stream>>>(c2w, wB2);
  qw_pack<<<1792, 256, 0, stream>>>(Qw, qB);
  rq_pack<<<238, 256, 0, stream>>>(Rw, Qw, rB, qrB);
  conv1_mfma<<<1024, 256, 0, stream>>>(x1, x2, wB1, part1, pmax1, pmin1);
  bn_finalize<<<64, 256, 0, stream>>>(part1, bn1g, bn1b, 1.f/1048576.f, bn1);
  conv2_mfma<<<1024, 256, 0, stream>>>(pmax1, pmin1, bn1, wB2, part2, pmax2, pmin2);
  bn_finalize<<<64, 256, 0, stream>>>(part2, bn2g, bn2b, 1.f/262144.f, bn2);
  preq_mfma<<<dim3(16,16), 256, 0, stream>>>(pmax2, pmin2, bn2, qB, pqpart);
  preq_reduce<<<400, 256, 0, stream>>>(pqpart, Qb, preQ2);
  rnn_fused<<<1, 512, 0, stream>>>(preQ2, rB, qrB, Rb, Ow, Ob, f1w, f1b, f2w, f2b, outp);
}